// Round 5
// baseline (136.674 us; speedup 1.0000x reference)
//
#include <hip/hip_runtime.h>
#include <hip/hip_bf16.h>

typedef unsigned short u16;
typedef unsigned int u32;
typedef __attribute__((ext_vector_type(8))) short short8;
typedef __attribute__((ext_vector_type(4))) float f32x4;

// Round-to-nearest-even f32 -> bf16 bit pattern.
__device__ __forceinline__ u16 f2bf(float f) {
    union { float f; u32 u; } c; c.f = f;
    u32 x = c.u;
    return (u16)((x + 0x7fffu + ((x >> 16) & 1u)) >> 16);
}

// Async global->LDS, 16 bytes per lane. LDS dest must be wave-uniform base
// (HW writes base + lane*16); global src is per-lane.
__device__ __forceinline__ void gload16(const void* g, void* l) {
    __builtin_amdgcn_global_load_lds((const __attribute__((address_space(1))) void*)g,
                                     (__attribute__((address_space(3))) void*)l,
                                     16, 0, 0);
}

// All f32->bf16 conversions in one launch: blocks 0..4095 convert x,
// blocks 4096..8191 convert the four 1024x1024 weights (Wq,Wk,Wv->wqkv; Wo->wob).
__global__ void cvt_all_kernel(const float* __restrict__ x,
                               const float* __restrict__ wq, const float* __restrict__ wk,
                               const float* __restrict__ wv, const float* __restrict__ wo,
                               u16* __restrict__ xb, u16* __restrict__ wqkv,
                               u16* __restrict__ wob) {
    int bid = blockIdx.x;
    const float* src;
    u16* dst;
    int i;
    if (bid < 4096) {
        src = x; dst = xb;
        i = bid * 256 + threadIdx.x;
    } else {
        int w = (bid - 4096) >> 10;
        src = (w == 0) ? wq : (w == 1) ? wk : (w == 2) ? wv : wo;
        dst = (w < 3) ? (wqkv + (size_t)w * 1048576) : wob;
        i = ((bid - 4096) & 1023) * 256 + threadIdx.x;
    }
    float4 v = reinterpret_cast<const float4*>(src)[i];
    ushort4 o;
    o.x = f2bf(v.x); o.y = f2bf(v.y); o.z = f2bf(v.z); o.w = f2bf(v.w);
    reinterpret_cast<ushort4*>(dst)[i] = o;
}

// C(4096 x Ncols) = A(4096x1024) * B^T, B row-major (Ncols x 1024).
// m97 structure: global_load_lds dwordx4 staging, linear LDS + XOR-swizzled reads.
// MODE 0: f32 row-major to outf (Ncols=1024)
// MODE 1: fused QKV (Ncols=3072): gj>>10 selects Q / K / V-transposed layout.
//         Q is pre-scaled by 0.125*log2(e) so attention scores land in log2 units.
template<int MODE>
__global__ __launch_bounds__(256, 3) void gemm_nt(const u16* __restrict__ A,
                                                  const u16* __restrict__ Bw,
                                                  u16* __restrict__ qkv,
                                                  float* __restrict__ outf) {
    constexpr int K = 1024;
    __shared__ __align__(16) u16 Al[128 * 64];
    __shared__ __align__(16) u16 Bl[128 * 64];
    const int tid = threadIdx.x;
    const int row0 = blockIdx.y * 128, col0 = blockIdx.x * 128;
    const int wid = tid >> 6, lane = tid & 63;
    const int wr = wid >> 1, wc = wid & 1;       // 2x2 waves, each 64x64 output
    const int lr = lane & 15, lg = lane >> 4;
    f32x4 acc[4][4] = {};

    const int srow = tid >> 3;                   // staging row within 32-row group
    const int sslotbase = tid & 7;

    for (int kt = 0; kt < K; kt += 64) {
        __syncthreads();                         // prev compute done before overwrite
        #pragma unroll
        for (int i = 0; i < 4; ++i) {
            int row = srow + i * 32;
            int srcslot = sslotbase ^ (row & 7); // pre-swizzled source -> linear LDS dest
            int ldsoff = i * 2048 + wid * 512;   // u16 units; wave-uniform
            gload16(&A[(size_t)(row0 + row) * K + kt + srcslot * 8], &Al[ldsoff]);
            gload16(&Bw[(size_t)(col0 + row) * K + kt + srcslot * 8], &Bl[ldsoff]);
        }
        __syncthreads();                         // vmcnt(0) drained by compiler

        #pragma unroll
        for (int ks = 0; ks < 2; ++ks) {
            short8 af[4], bfr[4];
            #pragma unroll
            for (int m = 0; m < 4; ++m) {
                int row = wr * 64 + m * 16 + lr;
                af[m] = *reinterpret_cast<const short8*>(
                    &Al[row * 64 + (((ks * 4 + lg) ^ (lr & 7)) << 3)]);
            }
            #pragma unroll
            for (int n = 0; n < 4; ++n) {
                int row = wc * 64 + n * 16 + lr;
                bfr[n] = *reinterpret_cast<const short8*>(
                    &Bl[row * 64 + (((ks * 4 + lg) ^ (lr & 7)) << 3)]);
            }
            #pragma unroll
            for (int m = 0; m < 4; ++m)
                #pragma unroll
                for (int n = 0; n < 4; ++n)
                    acc[m][n] = __builtin_amdgcn_mfma_f32_16x16x32_bf16(af[m], bfr[n], acc[m][n], 0, 0, 0);
        }
    }

    #pragma unroll
    for (int m = 0; m < 4; ++m) {
        #pragma unroll
        for (int n = 0; n < 4; ++n) {
            #pragma unroll
            for (int r = 0; r < 4; ++r) {
                int gi = row0 + wr * 64 + m * 16 + lg * 4 + r;   // row = (lane>>4)*4+reg
                int gj = col0 + wc * 64 + n * 16 + lr;           // col = lane&15
                float v = acc[m][n][r];
                if (MODE == 0) {
                    outf[(size_t)gi * 1024 + gj] = v;
                } else {
                    int mat = gj >> 10, c = gj & 1023;
                    int h = c >> 6, hd = c & 63;
                    int b = gi >> 11, s = gi & 2047;
                    if (mat == 0) v *= 0.18033688f;   // Q *= 0.125*log2(e)
                    size_t idx;
                    if (mat < 2) idx = (((size_t)(b * 16 + h) * 2048) + s) * 64 + hd;   // Q,K: (B,H,S,HD)
                    else         idx = (((size_t)(b * 16 + h) * 64) + hd) * 2048 + s;   // V: (B,H,HD,S)
                    qkv[(size_t)mat * 4194304 + idx] = f2bf(v);
                }
            }
        }
    }
}

// Flash attention + ALiBi + causal. ONE WAVE PER BLOCK, zero barriers.
// Each 64-thread block owns a balanced mirror pair of 16-row q-strips:
//   lo rows [16p,16p+16), hi rows [2048-16p-16, 2048-16p); units nt+nlo = 65 for all p.
// KVBLK=32, K/V double-buffered via global_load_lds + counted s_waitcnt vmcnt(8)
// (T4: loads stay in flight, no vmcnt(0) in the main loop, no __syncthreads at all).
// V and P use a superrow [32][64] layout with XOR slot swizzle (2-way max = free).
// LDS 18 KB -> 8 blocks/CU; grid 2048 = 8 independent waves/CU.
__global__ __launch_bounds__(64, 2) void attn_kernel(const u16* __restrict__ Q,
                                                     const u16* __restrict__ Kt,
                                                     const u16* __restrict__ VT,
                                                     u16* __restrict__ attn) {
    constexpr int S = 2048;
    __shared__ __align__(16) u16 Kl[2][32 * 64];   // [kv 32][hd 64]
    __shared__ __align__(16) u16 Vl[2][32 * 64];   // superrow: row sr holds d=2sr,2sr+1
    __shared__ __align__(16) u16 Pl[2][8 * 64];    // per strip; superrow: 2 q-rows/row
    const int gid = blockIdx.x;
    const int xcd = gid & 7, idx = gid >> 3;
    const int bh = xcd * 4 + (idx >> 6);           // each XCD sees 4 bh (K/V L2-fit)
    const int p  = idx & 63;                       // pair index 0..63
    const int b = bh >> 4, h = bh & 15;
    const int lane = threadIdx.x;
    const int lr = lane & 15, lg = lane >> 4;
    const float slope2 = exp2f(-0.5f * (float)(h + 1)) * 1.44269504f;  // slope*log2(e)
    const int nt  = (2079 - 16 * p) >> 5;          // hi strip needs tiles 0..nt-1
    const int nlo = (p >> 1) + 1;                  // lo strip active for t < nlo
    const int rowlo = 16 * p;
    const int rowhi = S - 16 * p - 16;
    const size_t qkbase = (size_t)bh * S * 64;
    const size_t vbase  = (size_t)bh * 64 * S;

    // Q fragments (already scaled by 0.125*log2e in the GEMM epilogue)
    short8 qf[2][2];
    #pragma unroll
    for (int st = 0; st < 2; ++st) {
        int rb = st ? rowhi : rowlo;
        #pragma unroll
        for (int ks = 0; ks < 2; ++ks)
            qf[st][ks] = *reinterpret_cast<const short8*>(
                &Q[qkbase + (size_t)(rb + lr) * 64 + ks * 32 + lg * 8]);
    }

    // Running ALiBi bias (log2 units) as MFMA C-init; decremented 32*slope2 per tile.
    const f32x4 bstep4 = {slope2 * 32.f, slope2 * 32.f, slope2 * 32.f, slope2 * 32.f};
    f32x4 bias[2][2];
    #pragma unroll
    for (int st = 0; st < 2; ++st) {
        int rb = st ? rowhi : rowlo;
        int kv0i = (st ? (nt - 1) : (nlo - 1)) * 32;
        #pragma unroll
        for (int n = 0; n < 2; ++n)
            #pragma unroll
            for (int r = 0; r < 4; ++r)
                bias[st][n][r] = slope2 * (float)(kv0i + n * 16 + lr - rb - lg * 4 - r);
    }

    float m_run[2][4];
    f32x4 o_acc[2][4] = {};
    f32x4 l_acc[2] = {};
    #pragma unroll
    for (int st = 0; st < 2; ++st)
        #pragma unroll
        for (int r = 0; r < 4; ++r) m_run[st][r] = -1e30f;

    short8 bones = (short8)(short)0x3F80;          // bf16 1.0 splat (l = P @ ones)

    const int sR = lane >> 3;                      // 0..7 staging row
    const int sS = lane & 7;                       // staging slot

    // Stage K tile [32][64] and V superrow tile [32][64] (8 gload16/lane).
    // Linear LDS dest; source pre-swizzled so reads can XOR-swizzle (rule #21).
    #define STAGE(buf, kv)                                                              \
        do {                                                                            \
            _Pragma("unroll")                                                           \
            for (int i_ = 0; i_ < 4; ++i_) {                                            \
                int row_ = sR + i_ * 8;                                                 \
                int ss_ = sS ^ (row_ & 7);                                              \
                gload16(&Kt[qkbase + (size_t)((kv) * 32 + row_) * 64 + ss_ * 8],        \
                        &Kl[buf][i_ * 512]);                                            \
                gload16(&VT[vbase + (size_t)(row_ * 2 + (ss_ >> 2)) * S + (kv) * 32     \
                            + (ss_ & 3) * 8],                                           \
                        &Vl[buf][i_ * 512]);                                            \
            }                                                                           \
        } while (0)

    // softmax for one strip (8 elems/lane): defer-max path has NO cross-lane ops.
    auto softmax = [&](f32x4* sacc, int st, bool domask, int rowbase, int kv0) {
        float* mr = m_run[st];
        if (domask) {
            #pragma unroll
            for (int n = 0; n < 2; ++n)
                #pragma unroll
                for (int r = 0; r < 4; ++r) {
                    int gc = kv0 + n * 16 + lr, gr = rowbase + lg * 4 + r;
                    if (gc > gr) sacc[n][r] = -1e30f;
                }
        }
        float mxl[4];
        #pragma unroll
        for (int r = 0; r < 4; ++r) mxl[r] = fmaxf(sacc[0][r], sacc[1][r]);
        int ok = (mxl[0] <= mr[0] + 8.f) && (mxl[1] <= mr[1] + 8.f) &&
                 (mxl[2] <= mr[2] + 8.f) && (mxl[3] <= mr[3] + 8.f);
        if (!__all(ok)) {
            #pragma unroll
            for (int r = 0; r < 4; ++r) {
                float mx = mxl[r];
                mx = fmaxf(mx, __shfl_xor(mx, 1));
                mx = fmaxf(mx, __shfl_xor(mx, 2));
                mx = fmaxf(mx, __shfl_xor(mx, 4));
                mx = fmaxf(mx, __shfl_xor(mx, 8));
                float mnew = fmaxf(mr[r], mx);
                float resc = exp2f(mr[r] - mnew);
                mr[r] = mnew;
                l_acc[st][r] *= resc;
                #pragma unroll
                for (int nd = 0; nd < 4; ++nd) o_acc[st][nd][r] *= resc;
            }
        }
        u16* pb = &Pl[st][0];
        #pragma unroll
        for (int r = 0; r < 4; ++r) {
            int pr = lg * 4 + r, sr2 = pr >> 1;
            #pragma unroll
            for (int n = 0; n < 2; ++n) {
                float pe = exp2f(sacc[n][r] - mr[r]);
                u32 bits = __float_as_uint(pe);         // round-half-up: cancels in O/l
                int pc = n * 16 + lr;
                int slot = (((pr & 1) * 4 + (pc >> 3)) ^ (sr2 & 7));
                pb[sr2 * 64 + slot * 8 + (pc & 7)] = (u16)((bits + 0x8000u) >> 16);
            }
        }
    };

    const int tstart = nt - 1;
    STAGE(tstart & 1, tstart);

    for (int t = tstart; t >= 0; --t) {            // diagonal-first
        const int cur = t & 1;
        const int kv0 = t * 32;
        if (t > 0) {
            STAGE(cur ^ 1, t - 1);                 // prefetch next (lower) tile
            asm volatile("s_waitcnt vmcnt(8)" ::: "memory");   // tile t ready; next in flight
        } else {
            asm volatile("s_waitcnt vmcnt(0)" ::: "memory");
        }
        const bool lo_on = (t < nlo);              // wave-uniform

        // ---- S = Q K^T (C-init = running ALiBi bias) ----
        f32x4 shi[2], slo[2];
        #pragma unroll
        for (int ks = 0; ks < 2; ++ks) {
            short8 bk[2];
            #pragma unroll
            for (int n = 0; n < 2; ++n)
                bk[n] = *reinterpret_cast<const short8*>(
                    &Kl[cur][(n * 16 + lr) * 64 + (((ks * 4 + lg) ^ (lr & 7)) << 3)]);
            #pragma unroll
            for (int n = 0; n < 2; ++n)
                shi[n] = __builtin_amdgcn_mfma_f32_16x16x32_bf16(qf[1][ks], bk[n],
                                                                 ks ? shi[n] : bias[1][n], 0, 0, 0);
            if (lo_on)
                #pragma unroll
                for (int n = 0; n < 2; ++n)
                    slo[n] = __builtin_amdgcn_mfma_f32_16x16x32_bf16(qf[0][ks], bk[n],
                                                                     ks ? slo[n] : bias[0][n], 0, 0, 0);
        }
        #pragma unroll
        for (int n = 0; n < 2; ++n) bias[1][n] = bias[1][n] - bstep4;

        softmax(shi, 1, t == nt - 1, rowhi, kv0);
        if (lo_on) {
            #pragma unroll
            for (int n = 0; n < 2; ++n) bias[0][n] = bias[0][n] - bstep4;
            softmax(slo, 0, t == nlo - 1, rowlo, kv0);
        }

        // ---- O += P V; l += P @ 1 (K-dim 32, single ks) ----
        {
            short8 bv[4];
            #pragma unroll
            for (int nd = 0; nd < 4; ++nd) {
                int d = nd * 16 + lr, srv = d >> 1;
                int slotv = (((d & 1) * 4 + lg) ^ (srv & 7));
                bv[nd] = *reinterpret_cast<const short8*>(&Vl[cur][srv * 64 + slotv * 8]);
            }
            const int psr = lr >> 1;
            const int pslot = (((lr & 1) * 4 + lg) ^ (psr & 7));
            short8 ah = *reinterpret_cast<const short8*>(&Pl[1][psr * 64 + pslot * 8]);
            #pragma unroll
            for (int nd = 0; nd < 4; ++nd)
                o_acc[1][nd] = __builtin_amdgcn_mfma_f32_16x16x32_bf16(ah, bv[nd], o_acc[1][nd], 0, 0, 0);
            l_acc[1] = __builtin_amdgcn_mfma_f32_16x16x32_bf16(ah, bones, l_acc[1], 0, 0, 0);
            if (lo_on) {
                short8 al = *reinterpret_cast<const short8*>(&Pl[0][psr * 64 + pslot * 8]);
                #pragma unroll
                for (int nd = 0; nd < 4; ++nd)
                    o_acc[0][nd] = __builtin_amdgcn_mfma_f32_16x16x32_bf16(al, bv[nd], o_acc[0][nd], 0, 0, 0);
                l_acc[0] = __builtin_amdgcn_mfma_f32_16x16x32_bf16(al, bones, l_acc[0], 0, 0, 0);
            }
        }
    }
    #undef STAGE

    // epilogue: O / l -> (B,S,D) bf16, D index = h*64 + hd
    #pragma unroll
    for (int st = 0; st < 2; ++st) {
        int rb = st ? rowhi : rowlo;
        #pragma unroll
        for (int r = 0; r < 4; ++r) {
            float inv = 1.f / l_acc[st][r];
            int gs = rb + lg * 4 + r;
            size_t obase = ((size_t)b * S + gs) * 1024 + h * 64;
            #pragma unroll
            for (int nd = 0; nd < 4; ++nd)
                attn[obase + nd * 16 + lr] = f2bf(o_acc[st][nd][r] * inv);
        }
    }
}

extern "C" void kernel_launch(void* const* d_in, const int* in_sizes, int n_in,
                              void* d_out, int out_size, void* d_ws, size_t ws_size,
                              hipStream_t stream) {
    const float* x  = (const float*)d_in[0];
    // d_in[1] is the causal mask (fixed tril) — implemented analytically.
    const float* Wq = (const float*)d_in[2];
    const float* Wk = (const float*)d_in[3];
    const float* Wv = (const float*)d_in[4];
    const float* Wo = (const float*)d_in[5];

    u16* xb   = (u16*)d_ws;            // 4,194,304  (also reused as Ab)
    u16* wqkv = xb + 4194304;          // 3,145,728  (Wq;Wk;Wv rows)
    u16* wob  = wqkv + 3145728;        // 1,048,576
    u16* Qb   = wob + 1048576;         // 4,194,304  (B,H,S,HD)
    u16* Kb   = Qb + 4194304;          // 4,194,304  (B,H,S,HD)
    u16* VTb  = Kb + 4194304;          // 4,194,304  (B,H,HD,S)
    u16* Ab   = xb;                    // attn output reuses xb (x no longer needed)

    cvt_all_kernel<<<8192, 256, 0, stream>>>(x, Wq, Wk, Wv, Wo, xb, wqkv, wob);

    gemm_nt<1><<<dim3(24, 32), 256, 0, stream>>>(xb, wqkv, Qb, nullptr);   // fused QKV

    attn_kernel<<<2048, 64, 0, stream>>>(Qb, Kb, VTb, Ab);

    gemm_nt<0><<<dim3(8, 32), 256, 0, stream>>>(Ab, wob, nullptr, (float*)d_out);
}

// Round 6
// 122.020 us; speedup vs baseline: 1.1201x; 1.1201x over previous
//
#include <hip/hip_runtime.h>
#include <hip/hip_bf16.h>

typedef unsigned short u16;
typedef unsigned int u32;
typedef __attribute__((ext_vector_type(8))) short short8;
typedef __attribute__((ext_vector_type(4))) float f32x4;

// Round-to-nearest-even f32 -> bf16 bit pattern.
__device__ __forceinline__ u16 f2bf(float f) {
    union { float f; u32 u; } c; c.f = f;
    u32 x = c.u;
    return (u16)((x + 0x7fffu + ((x >> 16) & 1u)) >> 16);
}

// Async global->LDS, 16 bytes per lane. LDS dest must be wave-uniform base
// (HW writes base + lane*16); global src is per-lane.
__device__ __forceinline__ void gload16(const void* g, void* l) {
    __builtin_amdgcn_global_load_lds((const __attribute__((address_space(1))) void*)g,
                                     (__attribute__((address_space(3))) void*)l,
                                     16, 0, 0);
}

// All f32->bf16 conversions in one launch: blocks 0..4095 convert x,
// blocks 4096..8191 convert the four 1024x1024 weights (Wq,Wk,Wv->wqkv; Wo->wob).
__global__ void cvt_all_kernel(const float* __restrict__ x,
                               const float* __restrict__ wq, const float* __restrict__ wk,
                               const float* __restrict__ wv, const float* __restrict__ wo,
                               u16* __restrict__ xb, u16* __restrict__ wqkv,
                               u16* __restrict__ wob) {
    int bid = blockIdx.x;
    const float* src;
    u16* dst;
    int i;
    if (bid < 4096) {
        src = x; dst = xb;
        i = bid * 256 + threadIdx.x;
    } else {
        int w = (bid - 4096) >> 10;
        src = (w == 0) ? wq : (w == 1) ? wk : (w == 2) ? wv : wo;
        dst = (w < 3) ? (wqkv + (size_t)w * 1048576) : wob;
        i = ((bid - 4096) & 1023) * 256 + threadIdx.x;
    }
    float4 v = reinterpret_cast<const float4*>(src)[i];
    ushort4 o;
    o.x = f2bf(v.x); o.y = f2bf(v.y); o.z = f2bf(v.z); o.w = f2bf(v.w);
    reinterpret_cast<ushort4*>(dst)[i] = o;
}

// C(4096 x Ncols) = A(4096x1024) * B^T, B row-major (Ncols x 1024).
// m97 structure: global_load_lds dwordx4 staging, linear LDS + XOR-swizzled reads.
// MODE 0: f32 row-major to outf (Ncols=1024)
// MODE 1: fused QKV (Ncols=3072): gj>>10 selects Q / K / V-transposed layout.
//         Q is pre-scaled by 0.125*log2(e) so attention scores land in log2 units.
template<int MODE>
__global__ __launch_bounds__(256, 3) void gemm_nt(const u16* __restrict__ A,
                                                  const u16* __restrict__ Bw,
                                                  u16* __restrict__ qkv,
                                                  float* __restrict__ outf) {
    constexpr int K = 1024;
    __shared__ __align__(16) u16 Al[128 * 64];
    __shared__ __align__(16) u16 Bl[128 * 64];
    const int tid = threadIdx.x;
    const int row0 = blockIdx.y * 128, col0 = blockIdx.x * 128;
    const int wid = tid >> 6, lane = tid & 63;
    const int wr = wid >> 1, wc = wid & 1;       // 2x2 waves, each 64x64 output
    const int lr = lane & 15, lg = lane >> 4;
    f32x4 acc[4][4] = {};

    const int srow = tid >> 3;                   // staging row within 32-row group
    const int sslotbase = tid & 7;

    for (int kt = 0; kt < K; kt += 64) {
        __syncthreads();                         // prev compute done before overwrite
        #pragma unroll
        for (int i = 0; i < 4; ++i) {
            int row = srow + i * 32;
            int srcslot = sslotbase ^ (row & 7); // pre-swizzled source -> linear LDS dest
            int ldsoff = i * 2048 + wid * 512;   // u16 units; wave-uniform
            gload16(&A[(size_t)(row0 + row) * K + kt + srcslot * 8], &Al[ldsoff]);
            gload16(&Bw[(size_t)(col0 + row) * K + kt + srcslot * 8], &Bl[ldsoff]);
        }
        __syncthreads();                         // vmcnt(0) drained by compiler

        #pragma unroll
        for (int ks = 0; ks < 2; ++ks) {
            short8 af[4], bfr[4];
            #pragma unroll
            for (int m = 0; m < 4; ++m) {
                int row = wr * 64 + m * 16 + lr;
                af[m] = *reinterpret_cast<const short8*>(
                    &Al[row * 64 + (((ks * 4 + lg) ^ (lr & 7)) << 3)]);
            }
            #pragma unroll
            for (int n = 0; n < 4; ++n) {
                int row = wc * 64 + n * 16 + lr;
                bfr[n] = *reinterpret_cast<const short8*>(
                    &Bl[row * 64 + (((ks * 4 + lg) ^ (lr & 7)) << 3)]);
            }
            #pragma unroll
            for (int m = 0; m < 4; ++m)
                #pragma unroll
                for (int n = 0; n < 4; ++n)
                    acc[m][n] = __builtin_amdgcn_mfma_f32_16x16x32_bf16(af[m], bfr[n], acc[m][n], 0, 0, 0);
        }
    }

    #pragma unroll
    for (int m = 0; m < 4; ++m) {
        #pragma unroll
        for (int n = 0; n < 4; ++n) {
            #pragma unroll
            for (int r = 0; r < 4; ++r) {
                int gi = row0 + wr * 64 + m * 16 + lg * 4 + r;   // row = (lane>>4)*4+reg
                int gj = col0 + wc * 64 + n * 16 + lr;           // col = lane&15
                float v = acc[m][n][r];
                if (MODE == 0) {
                    outf[(size_t)gi * 1024 + gj] = v;
                } else {
                    int mat = gj >> 10, c = gj & 1023;
                    int h = c >> 6, hd = c & 63;
                    int b = gi >> 11, s = gi & 2047;
                    if (mat == 0) v *= 0.18033688f;   // Q *= 0.125*log2(e)
                    size_t idx;
                    if (mat < 2) idx = (((size_t)(b * 16 + h) * 2048) + s) * 64 + hd;   // Q,K: (B,H,S,HD)
                    else         idx = (((size_t)(b * 16 + h) * 64) + hd) * 2048 + s;   // V: (B,H,HD,S)
                    qkv[(size_t)mat * 4194304 + idx] = f2bf(v);
                }
            }
        }
    }
}

// Flash attention + ALiBi + causal, balanced pairing, diagonal-first, defer-max,
// bias-in-MFMA-C, l-via-ones-MFMA. Round-4 structure with the sync upgraded:
// RAW s_barrier + COUNTED s_waitcnt vmcnt(8) (T4) -- prefetched global_load_lds
// stay in flight across the whole compute phase; no vmcnt(0)/lgkmcnt(0) drains.
// Each 128-thread block (2 waves) owns q-strip pair {p, mirror(p)}: 33 units for all p.
// Grid: 1024 blocks, XCD-swizzled (each XCD sees 4 bh -> K/V L2-resident).
__global__ __launch_bounds__(128, 2) void attn_kernel(const u16* __restrict__ Q,
                                                      const u16* __restrict__ Kt,
                                                      const u16* __restrict__ VT,
                                                      u16* __restrict__ attn) {
    constexpr int S = 2048;
    __shared__ __align__(16) u16 Kl[2][64 * 64];
    __shared__ __align__(16) u16 Vl[2][64 * 64];
    __shared__ __align__(16) u16 Pl[4][16 * 64];   // [wid*2+strip]
    const int gid = blockIdx.x;
    const int base = gid >> 3, xcd = gid & 7;
    const int bh = xcd * 4 + (base >> 5);          // XCD x gets bh in [4x, 4x+4)
    const int p  = base & 31;                      // pair index 0..31
    const int b = bh >> 4, h = bh & 15;
    const int tid = threadIdx.x, wid = tid >> 6, lane = tid & 63;
    const int lr = lane & 15, lg = lane >> 4;
    const float slope2 = exp2f(-0.5f * (float)(h + 1)) * 1.44269504f;  // slope*log2(e)
    const int nt  = (2111 - 32 * p) >> 6;          // hi strip needs tiles 0..nt-1
    const int nlo = ((32 * p + 31) >> 6) + 1;      // lo strip active for t < nlo
    const int rowlo = 32 * p + wid * 16;
    const int rowhi = S - 32 * p - 32 + wid * 16;
    const size_t qkbase = (size_t)bh * S * 64;
    const size_t vbase  = (size_t)bh * 64 * S;

    // Q fragments (already scaled by 0.125*log2e in the GEMM epilogue)
    short8 qf[2][2];
    #pragma unroll
    for (int st = 0; st < 2; ++st) {
        int rb = st ? rowhi : rowlo;
        #pragma unroll
        for (int ks = 0; ks < 2; ++ks)
            qf[st][ks] = *reinterpret_cast<const short8*>(
                &Q[qkbase + (size_t)(rb + lr) * 64 + ks * 32 + lg * 8]);
    }

    // Running ALiBi bias (log2 units) as MFMA C-init; decremented 64*slope2 per tile.
    const f32x4 bstep4 = {slope2 * 64.f, slope2 * 64.f, slope2 * 64.f, slope2 * 64.f};
    f32x4 bias[2][4];
    #pragma unroll
    for (int st = 0; st < 2; ++st) {
        int rb = st ? rowhi : rowlo;
        int kv0i = (st ? (nt - 1) : (nlo - 1)) * 64;
        #pragma unroll
        for (int n = 0; n < 4; ++n)
            #pragma unroll
            for (int r = 0; r < 4; ++r)
                bias[st][n][r] = slope2 * (float)(kv0i + n * 16 + lr - rb - lg * 4 - r);
    }

    float m_run[2][4];
    f32x4 o_acc[2][4] = {};
    f32x4 l_acc[2] = {};
    #pragma unroll
    for (int st = 0; st < 2; ++st)
        #pragma unroll
        for (int r = 0; r < 4; ++r) m_run[st][r] = -1e30f;

    short8 bones = (short8)(short)0x3F80;          // bf16 1.0 splat (l = P @ ones)

    const int srow = tid >> 3;    // 0..15
    const int sslot = tid & 7;

    // 8 gload16 per wave per tile (K: 4, V: 4).
    #define STAGE(buf, kv)                                                          \
        do {                                                                        \
            _Pragma("unroll")                                                       \
            for (int i_ = 0; i_ < 4; ++i_) {                                        \
                int row_ = srow + i_ * 16;                                          \
                int ss_ = sslot ^ (row_ & 7);                                       \
                int lo_ = i_ * 1024 + wid * 512;                                    \
                gload16(&Kt[qkbase + (size_t)((kv) * 64 + row_) * 64 + ss_ * 8],    \
                        &Kl[buf][lo_]);                                             \
                gload16(&VT[vbase + (size_t)row_ * S + (kv) * 64 + ss_ * 8],        \
                        &Vl[buf][lo_]);                                             \
            }                                                                       \
        } while (0)

    // softmax for one strip: defer-max common path has NO cross-lane ops.
    auto softmax = [&](f32x4* sacc, int st, bool domask, int rowbase, int kv0) {
        float* mr = m_run[st];
        if (domask) {
            #pragma unroll
            for (int n = 0; n < 4; ++n)
                #pragma unroll
                for (int r = 0; r < 4; ++r) {
                    int gc = kv0 + n * 16 + lr, gr = rowbase + lg * 4 + r;
                    if (gc > gr) sacc[n][r] = -1e30f;
                }
        }
        float mxl[4];
        #pragma unroll
        for (int r = 0; r < 4; ++r)
            mxl[r] = fmaxf(fmaxf(sacc[0][r], sacc[1][r]), fmaxf(sacc[2][r], sacc[3][r]));
        int ok = (mxl[0] <= mr[0] + 8.f) && (mxl[1] <= mr[1] + 8.f) &&
                 (mxl[2] <= mr[2] + 8.f) && (mxl[3] <= mr[3] + 8.f);
        if (!__all(ok)) {
            #pragma unroll
            for (int r = 0; r < 4; ++r) {
                float mx = mxl[r];
                mx = fmaxf(mx, __shfl_xor(mx, 1));
                mx = fmaxf(mx, __shfl_xor(mx, 2));
                mx = fmaxf(mx, __shfl_xor(mx, 4));
                mx = fmaxf(mx, __shfl_xor(mx, 8));
                float mnew = fmaxf(mr[r], mx);
                float resc = exp2f(mr[r] - mnew);
                mr[r] = mnew;
                l_acc[st][r] *= resc;
                #pragma unroll
                for (int nd = 0; nd < 4; ++nd) o_acc[st][nd][r] *= resc;
            }
        }
        u16* pb = &Pl[wid * 2 + st][0];
        #pragma unroll
        for (int r = 0; r < 4; ++r) {
            int pr = lg * 4 + r;
            #pragma unroll
            for (int n = 0; n < 4; ++n) {
                float pe = exp2f(sacc[n][r] - mr[r]);
                // round-half-up cvt: bias cancels exactly in O/l (same P feeds both)
                u32 bits = __float_as_uint(pe);
                int pc = n * 16 + lr;
                pb[pr * 64 + (((pc >> 3) ^ (pr & 7)) << 3) + (pc & 7)] =
                    (u16)((bits + 0x8000u) >> 16);
            }
        }
    };

    const int tstart = nt - 1;
    STAGE(tstart & 1, tstart);

    for (int t = tstart; t >= 0; --t) {          // diagonal-first
        const int cur = t & 1;
        const int kv0 = t * 64;
        if (t > 0) {
            STAGE(cur ^ 1, t - 1);               // prefetch next (lower) tile
            asm volatile("s_waitcnt vmcnt(8)" ::: "memory");   // my tile-t loads landed
        } else {
            asm volatile("s_waitcnt vmcnt(0)" ::: "memory");
        }
        __builtin_amdgcn_s_barrier();            // all waves' tile-t loads landed
        const bool lo_on = (t < nlo);            // block-uniform

        // ---- S = Q K^T (C-init = running ALiBi bias) ----
        f32x4 shi[4], slo[4];
        __builtin_amdgcn_s_setprio(1);
        #pragma unroll
        for (int ks = 0; ks < 2; ++ks) {
            const int sz = ((ks * 4 + lg) ^ (lr & 7)) << 3;
            short8 bk[4];
            #pragma unroll
            for (int n = 0; n < 4; ++n)
                bk[n] = *reinterpret_cast<const short8*>(&Kl[cur][(n * 16 + lr) * 64 + sz]);
            #pragma unroll
            for (int n = 0; n < 4; ++n)
                shi[n] = __builtin_amdgcn_mfma_f32_16x16x32_bf16(qf[1][ks], bk[n],
                                                                 ks ? shi[n] : bias[1][n], 0, 0, 0);
            if (lo_on)
                #pragma unroll
                for (int n = 0; n < 4; ++n)
                    slo[n] = __builtin_amdgcn_mfma_f32_16x16x32_bf16(qf[0][ks], bk[n],
                                                                     ks ? slo[n] : bias[0][n], 0, 0, 0);
        }
        __builtin_amdgcn_s_setprio(0);
        #pragma unroll
        for (int n = 0; n < 4; ++n) bias[1][n] = bias[1][n] - bstep4;

        softmax(shi, 1, t == nt - 1, rowhi, kv0);
        if (lo_on) {
            #pragma unroll
            for (int n = 0; n < 4; ++n) bias[0][n] = bias[0][n] - bstep4;
            softmax(slo, 0, t == nlo - 1, rowlo, kv0);
        }

        // ---- O += P V; l += P @ 1 ----
        __builtin_amdgcn_s_setprio(1);
        #pragma unroll
        for (int ks = 0; ks < 2; ++ks) {
            const int sz = ((ks * 4 + lg) ^ (lr & 7)) << 3;
            short8 bv[4];
            #pragma unroll
            for (int nd = 0; nd < 4; ++nd)
                bv[nd] = *reinterpret_cast<const short8*>(&Vl[cur][(nd * 16 + lr) * 64 + sz]);
            short8 ah = *reinterpret_cast<const short8*>(&Pl[wid * 2 + 1][lr * 64 + sz]);
            #pragma unroll
            for (int nd = 0; nd < 4; ++nd)
                o_acc[1][nd] = __builtin_amdgcn_mfma_f32_16x16x32_bf16(ah, bv[nd], o_acc[1][nd], 0, 0, 0);
            l_acc[1] = __builtin_amdgcn_mfma_f32_16x16x32_bf16(ah, bones, l_acc[1], 0, 0, 0);
            if (lo_on) {
                short8 al = *reinterpret_cast<const short8*>(&Pl[wid * 2 + 0][lr * 64 + sz]);
                #pragma unroll
                for (int nd = 0; nd < 4; ++nd)
                    o_acc[0][nd] = __builtin_amdgcn_mfma_f32_16x16x32_bf16(al, bv[nd], o_acc[0][nd], 0, 0, 0);
                l_acc[0] = __builtin_amdgcn_mfma_f32_16x16x32_bf16(al, bones, l_acc[0], 0, 0, 0);
            }
        }
        __builtin_amdgcn_s_setprio(0);
        __builtin_amdgcn_s_barrier();            // all waves done with buf[cur];
                                                 // next iter's STAGE may overwrite it
    }
    #undef STAGE

    // epilogue: O / l -> (B,S,D) bf16, D index = h*64 + hd
    #pragma unroll
    for (int st = 0; st < 2; ++st) {
        int rb = st ? rowhi : rowlo;
        #pragma unroll
        for (int r = 0; r < 4; ++r) {
            float inv = 1.f / l_acc[st][r];
            int gs = rb + lg * 4 + r;
            size_t obase = ((size_t)b * S + gs) * 1024 + h * 64;
            #pragma unroll
            for (int nd = 0; nd < 4; ++nd)
                attn[obase + nd * 16 + lr] = f2bf(o_acc[st][nd][r] * inv);
        }
    }
}

extern "C" void kernel_launch(void* const* d_in, const int* in_sizes, int n_in,
                              void* d_out, int out_size, void* d_ws, size_t ws_size,
                              hipStream_t stream) {
    const float* x  = (const float*)d_in[0];
    // d_in[1] is the causal mask (fixed tril) — implemented analytically.
    const float* Wq = (const float*)d_in[2];
    const float* Wk = (const float*)d_in[3];
    const float* Wv = (const float*)d_in[4];
    const float* Wo = (const float*)d_in[5];

    u16* xb   = (u16*)d_ws;            // 4,194,304  (also reused as Ab)
    u16* wqkv = xb + 4194304;          // 3,145,728  (Wq;Wk;Wv rows)
    u16* wob  = wqkv + 3145728;        // 1,048,576
    u16* Qb   = wob + 1048576;         // 4,194,304  (B,H,S,HD)
    u16* Kb   = Qb + 4194304;          // 4,194,304  (B,H,S,HD)
    u16* VTb  = Kb + 4194304;          // 4,194,304  (B,H,HD,S)
    u16* Ab   = xb;                    // attn output reuses xb (x no longer needed)

    cvt_all_kernel<<<8192, 256, 0, stream>>>(x, Wq, Wk, Wv, Wo, xb, wqkv, wob);

    gemm_nt<1><<<dim3(24, 32), 256, 0, stream>>>(xb, wqkv, Qb, nullptr);   // fused QKV

    attn_kernel<<<1024, 128, 0, stream>>>(Qb, Kb, VTb, Ab);

    gemm_nt<0><<<dim3(8, 32), 256, 0, stream>>>(Ab, wob, nullptr, (float*)d_out);
}